// Round 6
// baseline (166.448 us; speedup 1.0000x reference)
//
#include <hip/hip_runtime.h>

#define N_NODES 50000
#define N_EDGES 1200000
#define N_TILES (N_NODES / 16)     // 3125, exact
#define W1T_STRIDE 72              // bf16 elems per j-row in LDS (16B aligned)
#define NCHUNKS (N_EDGES / 32)     // 37500 chunks of 32 edges
#define EDGE_WAVES ((NCHUNKS + 1) / 2)        // 18750 one-shot waves (1 pair each)
#define EDGE_BLOCKS ((EDGE_WAVES + 3) / 4)    // 4688

typedef __attribute__((ext_vector_type(8))) short short8;   // 8 bf16
typedef __attribute__((ext_vector_type(4))) float floatx4;  // MFMA acc

__device__ __forceinline__ unsigned short f32_to_bf16(float f) {
    unsigned int v = __float_as_uint(f);
    unsigned int r = v + 0x7FFFu + ((v >> 16) & 1u);
    return (unsigned short)(r >> 16);
}
__device__ __forceinline__ float bf16_to_f32(unsigned short s) {
    return __uint_as_float(((unsigned int)s) << 16);
}
__device__ __forceinline__ unsigned int pack_bf16x2(float lo, float hi) {
    return (unsigned int)f32_to_bf16(lo) | ((unsigned int)f32_to_bf16(hi) << 16);
}

// ---------------------------------------------------------------------------
// Kernel 1: zero `out` + layer-1 precompute as MFMA GEMM (round-4 verified).
// P layout per node = 64 bf16: ushort p = 2n+g in each 32-ushort half holds
// feature (n + 16g); stores are coalesced dwords. Edge kernel compensates by
// loading W2 fragments with the matching permutation F(q,i)=4q+(i>>1)+16(i&1).
// ---------------------------------------------------------------------------
__global__ __launch_bounds__(256) void precompute_P_mfma(
    const float* __restrict__ x, const float* __restrict__ W1,
    const float* __restrict__ b1, unsigned short* __restrict__ P,
    float* __restrict__ out)
{
    const int tid  = threadIdx.x;
    const int gtid = blockIdx.x * 256 + tid;

    // zero the output accumulator (harness poisons it with 0xAA)
    for (int i = gtid; i < N_NODES; i += gridDim.x * 256)
        out[i] = 0.0f;

    __shared__ unsigned short W1t[64 * W1T_STRIDE];   // 9216 B
    for (int e = tid; e < 128 * 32; e += 256) {
        const int kp = e >> 5, jp = e & 31;
        W1t[((kp < 64) ? jp : jp + 32) * W1T_STRIDE + (kp & 63)] =
            f32_to_bf16(W1[e]);
    }
    __syncthreads();

    const int lane = tid & 63;
    const int n = lane & 15;
    const int q = lane >> 4;

    short8 bw[4][2];
    #pragma unroll
    for (int G = 0; G < 4; ++G)
        #pragma unroll
        for (int h = 0; h < 2; ++h)
            bw[G][h] = *(const short8*)
                &W1t[(n + 16 * G) * W1T_STRIDE + h * 32 + q * 8];
    const float bias0 = b1[n], bias1 = b1[n + 16];

    unsigned int* P32 = (unsigned int*)P;
    const int wid0   = blockIdx.x * 4 + (tid >> 6);
    const int stride = gridDim.x * 4;
    for (int tile = wid0; tile < N_TILES; tile += stride) {
        const int node = tile * 16 + n;
        const float4* xp  = (const float4*)(x + (size_t)node * 64 + q * 8);
        const float4 xa = xp[0], xb = xp[1];
        const float4* xp2 = (const float4*)(x + (size_t)node * 64 + 32 + q * 8);
        const float4 xc = xp2[0], xd = xp2[1];

        short8 a0, a1;
        a0[0] = (short)f32_to_bf16(xa.x); a0[1] = (short)f32_to_bf16(xa.y);
        a0[2] = (short)f32_to_bf16(xa.z); a0[3] = (short)f32_to_bf16(xa.w);
        a0[4] = (short)f32_to_bf16(xb.x); a0[5] = (short)f32_to_bf16(xb.y);
        a0[6] = (short)f32_to_bf16(xb.z); a0[7] = (short)f32_to_bf16(xb.w);
        a1[0] = (short)f32_to_bf16(xc.x); a1[1] = (short)f32_to_bf16(xc.y);
        a1[2] = (short)f32_to_bf16(xc.z); a1[3] = (short)f32_to_bf16(xc.w);
        a1[4] = (short)f32_to_bf16(xd.x); a1[5] = (short)f32_to_bf16(xd.y);
        a1[6] = (short)f32_to_bf16(xd.z); a1[7] = (short)f32_to_bf16(xd.w);

        floatx4 acc[4];
        #pragma unroll
        for (int G = 0; G < 4; ++G) {
            const float bi = (G == 0) ? bias0 : (G == 1) ? bias1 : 0.0f;
            acc[G] = (floatx4){bi, bi, bi, bi};
            acc[G] = __builtin_amdgcn_mfma_f32_16x16x32_bf16(a0, bw[G][0], acc[G], 0, 0, 0);
            acc[G] = __builtin_amdgcn_mfma_f32_16x16x32_bf16(a1, bw[G][1], acc[G], 0, 0, 0);
        }
        #pragma unroll
        for (int r = 0; r < 4; ++r) {
            const int nr = tile * 16 + q * 4 + r;
            P32[(size_t)nr * 32 + n]      = pack_bf16x2(acc[0][r], acc[1][r]);
            P32[(size_t)nr * 32 + 16 + n] = pack_bf16x2(acc[2][r], acc[3][r]);
        }
    }
}

// ---------------------------------------------------------------------------
// Kernel 2: per-edge layers 2+3 via MFMA + direct scatter-add.
// One-shot: each wave owns exactly 2 chunks (4 MFMA tiles, 64 edges), all
// 8 random 16B P-gathers issued together; 18750 waves for max TLP.
// ---------------------------------------------------------------------------
__global__ __launch_bounds__(256, 4) void edge_mlp_mfma(
    const int* __restrict__ row, const int* __restrict__ col,
    const float* __restrict__ u,
    const float* __restrict__ W2, const float* __restrict__ b2,
    const float* __restrict__ W3, const float* __restrict__ b3,
    const unsigned short* __restrict__ P, float* __restrict__ out)
{
    const int tid  = threadIdx.x;
    const int lane = tid & 63;
    const int n = lane & 15;
    const int q = lane >> 4;

    const int wave = (blockIdx.x * 256 + tid) >> 6;
    const int c = wave * 2;                      // first chunk of the pair
    if (c >= NCHUNKS) return;

    // ---- index loads first (longest dependency chain) ----
    int rI[4], cI[4];
    #pragma unroll
    for (int t = 0; t < 4; ++t) {
        const int e = c * 32 + t * 16 + n;
        rI[t] = row[e];
        cI[t] = col[e];
    }
    // ---- atomic-phase edge data, issued early ----
    int r2[2]; float u2[2];
    if (n < 8) {
        #pragma unroll
        for (int p = 0; p < 2; ++p) {
            const int e2 = (c + p) * 32 + 16 * (n >> 2) + 4 * q + (n & 3);
            r2[p] = row[e2];
            u2[p] = u[col[e2]];
        }
    }

    // ---- W2 B-frags (P permutation F(q,i)); L1-resident broadcastish ----
    short8 bf0, bf1;
    #pragma unroll
    for (int i = 0; i < 8; ++i) {
        const int F = q * 4 + (i >> 1) + 16 * (i & 1);
        bf0[i] = (short)f32_to_bf16(W2[F * 32 + n]);
        bf1[i] = (short)f32_to_bf16(W2[F * 32 + n + 16]);
    }
    const float w3n0 = W3[n], w3n1 = W3[n + 16];
    const float b2n0 = b2[n], b2n1 = b2[n + 16];
    const float bias3 = b3[0];

    // ---- 8 random 16B P-gathers, all in flight ----
    short8 v1[4], v2[4];
    #pragma unroll
    for (int t = 0; t < 4; ++t) {
        v1[t] = *(const short8*)(P + (size_t)rI[t] * 64 + q * 8);
        v2[t] = *(const short8*)(P + (size_t)cI[t] * 64 + 32 + q * 8);
    }

    // ---- layers 2+3 ----
    float tr[4][4];
    #pragma unroll
    for (int t = 0; t < 4; ++t) {
        short8 a;
        #pragma unroll
        for (int i = 0; i < 8; ++i) {
            const float f1 = bf16_to_f32((unsigned short)v1[t][i]);
            const float f2 = bf16_to_f32((unsigned short)v2[t][i]);
            a[i] = (short)f32_to_bf16(fmaxf(f1 + f2, 0.0f));
        }
        floatx4 d0 = {b2n0, b2n0, b2n0, b2n0};
        floatx4 d1 = {b2n1, b2n1, b2n1, b2n1};
        d0 = __builtin_amdgcn_mfma_f32_16x16x32_bf16(a, bf0, d0, 0, 0, 0);
        d1 = __builtin_amdgcn_mfma_f32_16x16x32_bf16(a, bf1, d1, 0, 0, 0);
        #pragma unroll
        for (int r = 0; r < 4; ++r)
            tr[t][r] = fmaxf(d0[r], 0.0f) * w3n0 + fmaxf(d1[r], 0.0f) * w3n1;
    }

    // ---- j-reduction over the 16 lanes of each quad ----
    #pragma unroll
    for (int mask = 1; mask < 16; mask <<= 1)
        #pragma unroll
        for (int t = 0; t < 4; ++t)
            #pragma unroll
            for (int r = 0; r < 4; ++r)
                tr[t][r] += __shfl_xor(tr[t][r], mask, 64);

    // ---- scatter: lane (q, n<8) owns edge (c+p)*32 + 16*(n>>2)+4q+(n&3) ----
    if (n < 8) {
        #pragma unroll
        for (int p = 0; p < 2; ++p) {
            const int tb = 2 * p;
            const float va0 = (n & 4) ? tr[tb + 1][0] : tr[tb][0];
            const float va1 = (n & 4) ? tr[tb + 1][1] : tr[tb][1];
            const float va2 = (n & 4) ? tr[tb + 1][2] : tr[tb][2];
            const float va3 = (n & 4) ? tr[tb + 1][3] : tr[tb][3];
            const float vb0 = (n & 2) ? va2 : va0;
            const float vb1 = (n & 2) ? va3 : va1;
            const float v   = (n & 1) ? vb1 : vb0;
            atomicAdd(out + r2[p], (v + bias3) * u2[p]);
        }
    }
}

extern "C" void kernel_launch(void* const* d_in, const int* in_sizes, int n_in,
                              void* d_out, int out_size, void* d_ws, size_t ws_size,
                              hipStream_t stream)
{
    const float* x    = (const float*)d_in[0];
    const int*   eidx = (const int*)  d_in[1];   // [2, E] int32
    const float* u    = (const float*)d_in[2];
    const float* W1   = (const float*)d_in[3];
    const float* b1   = (const float*)d_in[4];
    const float* W2   = (const float*)d_in[5];
    const float* b2   = (const float*)d_in[6];
    const float* W3   = (const float*)d_in[7];
    const float* b3   = (const float*)d_in[8];

    const int* row = eidx;
    const int* col = eidx + N_EDGES;

    unsigned short* P = (unsigned short*)d_ws;   // [N_NODES, 64] bf16 = 6.4 MB
    float* out = (float*)d_out;

    // Dispatch 1: zero out + precompute P
    precompute_P_mfma<<<512, 256, 0, stream>>>(x, W1, b1, P, out);

    // Dispatch 2: edge MLP + direct scatter, one-shot waves
    edge_mlp_mfma<<<EDGE_BLOCKS, 256, 0, stream>>>(
        row, col, u, W2, b2, W3, b3, P, out);
}

// Round 7
// 153.730 us; speedup vs baseline: 1.0827x; 1.0827x over previous
//
#include <hip/hip_runtime.h>

#define N_NODES 50000
#define N_EDGES 1200000
#define N_TILES (N_NODES / 16)   // 3125, exact
#define N_REP   16               // replicated atomic accumulators
#define REP_STRIDE 50064         // floats; de-aliases replica lines
#define W1T_STRIDE 72            // bf16 elems per j-row in LDS (16B aligned)
#define K1_BLOCKS 782            // 3128 waves >= 3125 tiles, one-shot
#define K2_BLOCKS 2048           // 8192 waves, ~4.6 chunks each

typedef __attribute__((ext_vector_type(8))) short short8;   // 8 bf16
typedef __attribute__((ext_vector_type(4))) float floatx4;  // MFMA acc

__device__ __forceinline__ unsigned short f32_to_bf16(float f) {
    unsigned int v = __float_as_uint(f);
    unsigned int r = v + 0x7FFFu + ((v >> 16) & 1u);
    return (unsigned short)(r >> 16);
}
__device__ __forceinline__ float bf16_to_f32(unsigned short s) {
    return __uint_as_float(((unsigned int)s) << 16);
}
__device__ __forceinline__ unsigned int pack_bf16x2(float lo, float hi) {
    return (unsigned int)f32_to_bf16(lo) | ((unsigned int)f32_to_bf16(hi) << 16);
}

// ---------------------------------------------------------------------------
// Kernel 1: zero replicas + layer-1 precompute as MFMA GEMM (round-4 proven).
// One 16-node tile per wave, one-shot. P layout per node = 64 bf16: ushort
// p = 2n+g in each 32-ushort half holds feature (n + 16g) -> coalesced dword
// stores; edge kernel loads W2 frags with matching F(q,i)=4q+(i>>1)+16(i&1).
// ---------------------------------------------------------------------------
__global__ __launch_bounds__(256) void precompute_P_mfma(
    const float* __restrict__ x, const float* __restrict__ W1,
    const float* __restrict__ b1, unsigned short* __restrict__ P,
    float* __restrict__ rep)
{
    const int tid  = threadIdx.x;
    const int gtid = blockIdx.x * 256 + tid;

    // zero the replica accumulators (harness poisons d_ws with 0xAA)
    for (int i = gtid; i < N_REP * REP_STRIDE; i += K1_BLOCKS * 256)
        rep[i] = 0.0f;

    __shared__ unsigned short W1t[64 * W1T_STRIDE];   // 9216 B
    for (int e = tid; e < 128 * 32; e += 256) {
        const int kp = e >> 5, jp = e & 31;
        W1t[((kp < 64) ? jp : jp + 32) * W1T_STRIDE + (kp & 63)] =
            f32_to_bf16(W1[e]);
    }
    __syncthreads();

    const int lane = tid & 63;
    const int n = lane & 15;
    const int q = lane >> 4;

    const int tile = blockIdx.x * 4 + (tid >> 6);
    if (tile >= N_TILES) return;

    short8 bw[4][2];
    #pragma unroll
    for (int G = 0; G < 4; ++G)
        #pragma unroll
        for (int h = 0; h < 2; ++h)
            bw[G][h] = *(const short8*)
                &W1t[(n + 16 * G) * W1T_STRIDE + h * 32 + q * 8];
    const float bias0 = b1[n], bias1 = b1[n + 16];

    const int node = tile * 16 + n;
    const float4* xp  = (const float4*)(x + (size_t)node * 64 + q * 8);
    const float4 xa = xp[0], xb = xp[1];
    const float4* xp2 = (const float4*)(x + (size_t)node * 64 + 32 + q * 8);
    const float4 xc = xp2[0], xd = xp2[1];

    short8 a0, a1;
    a0[0] = (short)f32_to_bf16(xa.x); a0[1] = (short)f32_to_bf16(xa.y);
    a0[2] = (short)f32_to_bf16(xa.z); a0[3] = (short)f32_to_bf16(xa.w);
    a0[4] = (short)f32_to_bf16(xb.x); a0[5] = (short)f32_to_bf16(xb.y);
    a0[6] = (short)f32_to_bf16(xb.z); a0[7] = (short)f32_to_bf16(xb.w);
    a1[0] = (short)f32_to_bf16(xc.x); a1[1] = (short)f32_to_bf16(xc.y);
    a1[2] = (short)f32_to_bf16(xc.z); a1[3] = (short)f32_to_bf16(xc.w);
    a1[4] = (short)f32_to_bf16(xd.x); a1[5] = (short)f32_to_bf16(xd.y);
    a1[6] = (short)f32_to_bf16(xd.z); a1[7] = (short)f32_to_bf16(xd.w);

    unsigned int* P32 = (unsigned int*)P;
    floatx4 acc[4];
    #pragma unroll
    for (int G = 0; G < 4; ++G) {
        const float bi = (G == 0) ? bias0 : (G == 1) ? bias1 : 0.0f;
        acc[G] = (floatx4){bi, bi, bi, bi};
        acc[G] = __builtin_amdgcn_mfma_f32_16x16x32_bf16(a0, bw[G][0], acc[G], 0, 0, 0);
        acc[G] = __builtin_amdgcn_mfma_f32_16x16x32_bf16(a1, bw[G][1], acc[G], 0, 0, 0);
    }
    #pragma unroll
    for (int r = 0; r < 4; ++r) {
        const int nr = tile * 16 + q * 4 + r;
        P32[(size_t)nr * 32 + n]      = pack_bf16x2(acc[0][r], acc[1][r]);
        P32[(size_t)nr * 32 + 16 + n] = pack_bf16x2(acc[2][r], acc[3][r]);
    }
}

// ---------------------------------------------------------------------------
// Kernel 2: per-edge layers 2+3 via MFMA + replicated scatter-add.
// Inner loop byte-identical to the round-4 kernel that measured 68 us with
// LDS_Block_Size 0 / VGPR 36 (tr[2][4]; no min-waves launch bound -> no
// alloca->LDS demotion). Only the grid is bumped 1024 -> 2048 blocks.
// ---------------------------------------------------------------------------
__global__ __launch_bounds__(256) void edge_mlp_mfma(
    const int* __restrict__ row, const int* __restrict__ col,
    const float* __restrict__ u,
    const float* __restrict__ W2, const float* __restrict__ b2,
    const float* __restrict__ W3, const float* __restrict__ b3,
    const unsigned short* __restrict__ P, float* __restrict__ rep)
{
    const int lane = threadIdx.x & 63;
    const int n = lane & 15;
    const int q = lane >> 4;

    short8 bf0, bf1;
    #pragma unroll
    for (int i = 0; i < 8; ++i) {
        const int F = q * 4 + (i >> 1) + 16 * (i & 1);   // feature in slot (q,i)
        bf0[i] = (short)f32_to_bf16(W2[F * 32 + n]);
        bf1[i] = (short)f32_to_bf16(W2[F * 32 + n + 16]);
    }
    const float w3n0 = W3[n], w3n1 = W3[n + 16];
    const float b2n0 = b2[n], b2n1 = b2[n + 16];
    const float bias3 = b3[0];

    const int wave   = (blockIdx.x * 256 + (int)threadIdx.x) >> 6;
    const int nwaves = gridDim.x * 4;
    const int nchunks = N_EDGES / 32;   // 37500, exact
    float* myrep = rep + (size_t)(wave & (N_REP - 1)) * REP_STRIDE;

    for (int ch = wave; ch < nchunks; ch += nwaves) {
        const int base0 = ch * 32;

        int rI[2], cI[2];
        #pragma unroll
        for (int t = 0; t < 2; ++t) {
            const int e = base0 + t * 16 + n;
            rI[t] = row[e];
            cI[t] = col[e];
        }
        int r2 = 0; float u2 = 0.0f;
        if (n < 8) {
            const int e2 = base0 + 16 * (n >> 2) + 4 * q + (n & 3);
            r2 = row[e2];
            u2 = u[col[e2]];
        }
        short8 v1[2], v2[2];
        #pragma unroll
        for (int t = 0; t < 2; ++t) {
            v1[t] = *(const short8*)(P + (size_t)rI[t] * 64 + q * 8);
            v2[t] = *(const short8*)(P + (size_t)cI[t] * 64 + 32 + q * 8);
        }

        float tr[2][4];
        #pragma unroll
        for (int t = 0; t < 2; ++t) {
            short8 a;
            #pragma unroll
            for (int i = 0; i < 8; ++i) {
                const float f1 = bf16_to_f32((unsigned short)v1[t][i]);
                const float f2 = bf16_to_f32((unsigned short)v2[t][i]);
                a[i] = (short)f32_to_bf16(fmaxf(f1 + f2, 0.0f));
            }
            floatx4 d0 = {b2n0, b2n0, b2n0, b2n0};
            floatx4 d1 = {b2n1, b2n1, b2n1, b2n1};
            d0 = __builtin_amdgcn_mfma_f32_16x16x32_bf16(a, bf0, d0, 0, 0, 0);
            d1 = __builtin_amdgcn_mfma_f32_16x16x32_bf16(a, bf1, d1, 0, 0, 0);
            #pragma unroll
            for (int r = 0; r < 4; ++r)
                tr[t][r] = fmaxf(d0[r], 0.0f) * w3n0 + fmaxf(d1[r], 0.0f) * w3n1;
        }

        #pragma unroll
        for (int mask = 1; mask < 16; mask <<= 1) {
            #pragma unroll
            for (int t = 0; t < 2; ++t)
                #pragma unroll
                for (int r = 0; r < 4; ++r)
                    tr[t][r] += __shfl_xor(tr[t][r], mask, 64);
        }

        if (n < 8) {
            const float va0 = (n & 4) ? tr[1][0] : tr[0][0];
            const float va1 = (n & 4) ? tr[1][1] : tr[0][1];
            const float va2 = (n & 4) ? tr[1][2] : tr[0][2];
            const float va3 = (n & 4) ? tr[1][3] : tr[0][3];
            const float vb0 = (n & 2) ? va2 : va0;
            const float vb1 = (n & 2) ? va3 : va1;
            const float v   = (n & 1) ? vb1 : vb0;
            atomicAdd(myrep + r2, (v + bias3) * u2);
        }
    }
}

// ---------------------------------------------------------------------------
// Kernel 3: sum the 16 replicas into the output (overwrites out fully).
// ---------------------------------------------------------------------------
__global__ __launch_bounds__(256) void reduce_out(
    const float* __restrict__ rep, float* __restrict__ out)
{
    const int i = blockIdx.x * 256 + (int)threadIdx.x;
    if (i < N_NODES) {
        float s = 0.0f;
        #pragma unroll
        for (int r = 0; r < N_REP; ++r)
            s += rep[(size_t)r * REP_STRIDE + i];
        out[i] = s;
    }
}

extern "C" void kernel_launch(void* const* d_in, const int* in_sizes, int n_in,
                              void* d_out, int out_size, void* d_ws, size_t ws_size,
                              hipStream_t stream)
{
    const float* x    = (const float*)d_in[0];
    const int*   eidx = (const int*)  d_in[1];   // [2, E] int32
    const float* u    = (const float*)d_in[2];
    const float* W1   = (const float*)d_in[3];
    const float* b1   = (const float*)d_in[4];
    const float* W2   = (const float*)d_in[5];
    const float* b2   = (const float*)d_in[6];
    const float* W3   = (const float*)d_in[7];
    const float* b3   = (const float*)d_in[8];

    const int* row = eidx;
    const int* col = eidx + N_EDGES;

    unsigned short* P = (unsigned short*)d_ws;                   // 6.40 MB
    float* rep = (float*)((char*)d_ws + (size_t)N_NODES * 128);  // 3.20 MB
    float* out = (float*)d_out;

    // Dispatch 1: zero replicas + precompute P (one tile per wave)
    precompute_P_mfma<<<K1_BLOCKS, 256, 0, stream>>>(x, W1, b1, P, rep);

    // Dispatch 2: edge MLP + replicated scatter
    edge_mlp_mfma<<<K2_BLOCKS, 256, 0, stream>>>(
        row, col, u, W2, b2, W3, b3, P, rep);

    // Dispatch 3: reduce replicas into out
    reduce_out<<<(N_NODES + 255) / 256, 256, 0, stream>>>(rep, out);
}

// Round 8
// 150.164 us; speedup vs baseline: 1.1084x; 1.0237x over previous
//
#include <hip/hip_runtime.h>

#define N_NODES 50000
#define N_EDGES 1200000
#define N_TILES (N_NODES / 16)   // 3125, exact
#define W1T_STRIDE 72            // bf16 elems per j-row in LDS (16B aligned)
#define K1_BLOCKS 782            // 3128 waves >= 3125 tiles, one-shot

#define N_BUCKETS 196            // ceil(50000/256) node buckets of 256
#define BUCKET_CAP 7168          // mean 6122, sigma ~78 -> 13 sigma headroom
#define CHUNKS_PER_WAVE 15       // 32-edge chunks per wave
#define EDGES_PER_BLOCK 1920     // 4 waves * 15 * 32
#define KA_BLOCKS 625            // 1.2M / 1920 exact

typedef __attribute__((ext_vector_type(8))) short short8;   // 8 bf16
typedef __attribute__((ext_vector_type(4))) float floatx4;  // MFMA acc

__device__ __forceinline__ unsigned short f32_to_bf16(float f) {
    unsigned int v = __float_as_uint(f);
    unsigned int r = v + 0x7FFFu + ((v >> 16) & 1u);
    return (unsigned short)(r >> 16);
}
__device__ __forceinline__ float bf16_to_f32(unsigned short s) {
    return __uint_as_float(((unsigned int)s) << 16);
}
__device__ __forceinline__ unsigned int pack_bf16x2(float lo, float hi) {
    return (unsigned int)f32_to_bf16(lo) | ((unsigned int)f32_to_bf16(hi) << 16);
}

// ---------------------------------------------------------------------------
// Kernel 1: zero bucket cursors + layer-1 precompute as MFMA GEMM (R4-proven).
// One 16-node tile per wave, one-shot. P layout per node = 64 bf16: ushort
// p = 2n+g in each 32-ushort half holds feature (n + 16g) -> coalesced dword
// stores; edge kernel loads W2 frags with matching F(q,i)=4q+(i>>1)+16(i&1).
// ---------------------------------------------------------------------------
__global__ __launch_bounds__(256) void precompute_P_mfma(
    const float* __restrict__ x, const float* __restrict__ W1,
    const float* __restrict__ b1, unsigned short* __restrict__ P,
    int* __restrict__ cursor)
{
    const int tid  = threadIdx.x;
    const int gtid = blockIdx.x * 256 + tid;

    if (gtid < N_BUCKETS) cursor[gtid] = 0;   // zero bucket cursors

    __shared__ unsigned short W1t[64 * W1T_STRIDE];   // 9216 B
    for (int e = tid; e < 128 * 32; e += 256) {
        const int kp = e >> 5, jp = e & 31;
        W1t[((kp < 64) ? jp : jp + 32) * W1T_STRIDE + (kp & 63)] =
            f32_to_bf16(W1[e]);
    }
    __syncthreads();

    const int lane = tid & 63;
    const int n = lane & 15;
    const int q = lane >> 4;

    const int tile = blockIdx.x * 4 + (tid >> 6);
    if (tile >= N_TILES) return;

    short8 bw[4][2];
    #pragma unroll
    for (int G = 0; G < 4; ++G)
        #pragma unroll
        for (int h = 0; h < 2; ++h)
            bw[G][h] = *(const short8*)
                &W1t[(n + 16 * G) * W1T_STRIDE + h * 32 + q * 8];
    const float bias0 = b1[n], bias1 = b1[n + 16];

    const int node = tile * 16 + n;
    const float4* xp  = (const float4*)(x + (size_t)node * 64 + q * 8);
    const float4 xa = xp[0], xb = xp[1];
    const float4* xp2 = (const float4*)(x + (size_t)node * 64 + 32 + q * 8);
    const float4 xc = xp2[0], xd = xp2[1];

    short8 a0, a1;
    a0[0] = (short)f32_to_bf16(xa.x); a0[1] = (short)f32_to_bf16(xa.y);
    a0[2] = (short)f32_to_bf16(xa.z); a0[3] = (short)f32_to_bf16(xa.w);
    a0[4] = (short)f32_to_bf16(xb.x); a0[5] = (short)f32_to_bf16(xb.y);
    a0[6] = (short)f32_to_bf16(xb.z); a0[7] = (short)f32_to_bf16(xb.w);
    a1[0] = (short)f32_to_bf16(xc.x); a1[1] = (short)f32_to_bf16(xc.y);
    a1[2] = (short)f32_to_bf16(xc.z); a1[3] = (short)f32_to_bf16(xc.w);
    a1[4] = (short)f32_to_bf16(xd.x); a1[5] = (short)f32_to_bf16(xd.y);
    a1[6] = (short)f32_to_bf16(xd.z); a1[7] = (short)f32_to_bf16(xd.w);

    unsigned int* P32 = (unsigned int*)P;
    floatx4 acc[4];
    #pragma unroll
    for (int G = 0; G < 4; ++G) {
        const float bi = (G == 0) ? bias0 : (G == 1) ? bias1 : 0.0f;
        acc[G] = (floatx4){bi, bi, bi, bi};
        acc[G] = __builtin_amdgcn_mfma_f32_16x16x32_bf16(a0, bw[G][0], acc[G], 0, 0, 0);
        acc[G] = __builtin_amdgcn_mfma_f32_16x16x32_bf16(a1, bw[G][1], acc[G], 0, 0, 0);
    }
    #pragma unroll
    for (int r = 0; r < 4; ++r) {
        const int nr = tile * 16 + q * 4 + r;
        P32[(size_t)nr * 32 + n]      = pack_bf16x2(acc[0][r], acc[1][r]);
        P32[(size_t)nr * 32 + 16 + n] = pack_bf16x2(acc[2][r], acc[3][r]);
    }
}

// ---------------------------------------------------------------------------
// Kernel 2: per-edge layers 2+3 via MFMA + BINNED scatter (no per-edge global
// atomics). Each block owns 1920 contiguous edges.
//  pass 1: LDS-rank every edge within its bucket (row >> 8), LDS atomics.
//  pass 1b: one global atomicAdd per (block, bucket) reserves slots.
//  pass 2: proven MFMA inner loop; owner lane packs (bf16 val | u8 row&255)
//          and stores it to buf[bucket * CAP + base + rank] — plain store.
// ---------------------------------------------------------------------------
__global__ __launch_bounds__(256) void edge_mlp_bin(
    const int* __restrict__ row, const int* __restrict__ col,
    const float* __restrict__ u,
    const float* __restrict__ W2, const float* __restrict__ b2,
    const float* __restrict__ W3, const float* __restrict__ b3,
    const unsigned short* __restrict__ P,
    unsigned int* __restrict__ buf, int* __restrict__ cursor)
{
    __shared__ unsigned short rankv[EDGES_PER_BLOCK];  // 3840 B
    __shared__ int hist[N_BUCKETS];
    __shared__ int base[N_BUCKETS];

    const int tid = threadIdx.x;
    for (int b = tid; b < N_BUCKETS; b += 256) hist[b] = 0;
    __syncthreads();

    const int blockStart = blockIdx.x * EDGES_PER_BLOCK;

    // ---- pass 1: per-block ranks via LDS atomics ----
    for (int i = tid; i < EDGES_PER_BLOCK; i += 256) {
        const int r = row[blockStart + i];
        rankv[i] = (unsigned short)atomicAdd(&hist[r >> 8], 1);
    }
    __syncthreads();

    // ---- pass 1b: reserve global slots (one atomic per block-bucket) ----
    for (int b = tid; b < N_BUCKETS; b += 256)
        base[b] = atomicAdd(&cursor[b], hist[b]);
    __syncthreads();

    // ---- pass 2: MLP compute + binned scatter ----
    const int lane = tid & 63;
    const int n = lane & 15;
    const int q = lane >> 4;
    const int wave = tid >> 6;

    short8 bf0, bf1;
    #pragma unroll
    for (int i = 0; i < 8; ++i) {
        const int F = q * 4 + (i >> 1) + 16 * (i & 1);   // feature in slot (q,i)
        bf0[i] = (short)f32_to_bf16(W2[F * 32 + n]);
        bf1[i] = (short)f32_to_bf16(W2[F * 32 + n + 16]);
    }
    const float w3n0 = W3[n], w3n1 = W3[n + 16];
    const float b2n0 = b2[n], b2n1 = b2[n + 16];
    const float bias3 = b3[0];

    #pragma unroll 1
    for (int ci = 0; ci < CHUNKS_PER_WAVE; ++ci) {
        const int cloc  = (wave * CHUNKS_PER_WAVE + ci) * 32;  // local chunk base
        const int base0 = blockStart + cloc;

        int rI[2], cI[2];
        #pragma unroll
        for (int t = 0; t < 2; ++t) {
            const int e = base0 + t * 16 + n;
            rI[t] = row[e];
            cI[t] = col[e];
        }
        int r2 = 0, eloc = 0; float u2 = 0.0f;
        if (n < 8) {
            eloc = cloc + 16 * (n >> 2) + 4 * q + (n & 3);
            const int e2 = blockStart + eloc;
            r2 = row[e2];
            u2 = u[col[e2]];
        }
        short8 v1[2], v2[2];
        #pragma unroll
        for (int t = 0; t < 2; ++t) {
            v1[t] = *(const short8*)(P + (size_t)rI[t] * 64 + q * 8);
            v2[t] = *(const short8*)(P + (size_t)cI[t] * 64 + 32 + q * 8);
        }

        float tr[2][4];
        #pragma unroll
        for (int t = 0; t < 2; ++t) {
            short8 a;
            #pragma unroll
            for (int i = 0; i < 8; ++i) {
                const float f1 = bf16_to_f32((unsigned short)v1[t][i]);
                const float f2 = bf16_to_f32((unsigned short)v2[t][i]);
                a[i] = (short)f32_to_bf16(fmaxf(f1 + f2, 0.0f));
            }
            floatx4 d0 = {b2n0, b2n0, b2n0, b2n0};
            floatx4 d1 = {b2n1, b2n1, b2n1, b2n1};
            d0 = __builtin_amdgcn_mfma_f32_16x16x32_bf16(a, bf0, d0, 0, 0, 0);
            d1 = __builtin_amdgcn_mfma_f32_16x16x32_bf16(a, bf1, d1, 0, 0, 0);
            #pragma unroll
            for (int r = 0; r < 4; ++r)
                tr[t][r] = fmaxf(d0[r], 0.0f) * w3n0 + fmaxf(d1[r], 0.0f) * w3n1;
        }

        #pragma unroll
        for (int mask = 1; mask < 16; mask <<= 1) {
            #pragma unroll
            for (int t = 0; t < 2; ++t)
                #pragma unroll
                for (int r = 0; r < 4; ++r)
                    tr[t][r] += __shfl_xor(tr[t][r], mask, 64);
        }

        if (n < 8) {
            const float va0 = (n & 4) ? tr[1][0] : tr[0][0];
            const float va1 = (n & 4) ? tr[1][1] : tr[0][1];
            const float va2 = (n & 4) ? tr[1][2] : tr[0][2];
            const float va3 = (n & 4) ? tr[1][3] : tr[0][3];
            const float vb0 = (n & 2) ? va2 : va0;
            const float vb1 = (n & 2) ? va3 : va1;
            const float v   = (n & 1) ? vb1 : vb0;
            const float val = (v + bias3) * u2;

            const int bin  = r2 >> 8;
            const int slot = base[bin] + (int)rankv[eloc];
            buf[(size_t)bin * BUCKET_CAP + slot] =
                ((unsigned int)f32_to_bf16(val) << 16) | (unsigned int)(r2 & 255);
        }
    }
}

// ---------------------------------------------------------------------------
// Kernel 3: one block per bucket — LDS fp32 reduce, write out directly.
// Every node belongs to exactly one bucket, so out needs no pre-zeroing.
// ---------------------------------------------------------------------------
__global__ __launch_bounds__(256) void bucket_reduce(
    const unsigned int* __restrict__ buf, const int* __restrict__ cursor,
    float* __restrict__ out)
{
    __shared__ float acc[256];
    const int b   = blockIdx.x;
    const int tid = threadIdx.x;
    acc[tid] = 0.0f;
    __syncthreads();

    const int cnt = cursor[b];
    const unsigned int* bb = buf + (size_t)b * BUCKET_CAP;
    for (int i = tid; i < cnt; i += 256) {
        const unsigned int ent = bb[i];
        atomicAdd(&acc[ent & 255u],
                  bf16_to_f32((unsigned short)(ent >> 16)));
    }
    __syncthreads();

    const int node = b * 256 + tid;
    if (node < N_NODES) out[node] = acc[tid];
}

extern "C" void kernel_launch(void* const* d_in, const int* in_sizes, int n_in,
                              void* d_out, int out_size, void* d_ws, size_t ws_size,
                              hipStream_t stream)
{
    const float* x    = (const float*)d_in[0];
    const int*   eidx = (const int*)  d_in[1];   // [2, E] int32
    const float* u    = (const float*)d_in[2];
    const float* W1   = (const float*)d_in[3];
    const float* b1   = (const float*)d_in[4];
    const float* W2   = (const float*)d_in[5];
    const float* b2   = (const float*)d_in[6];
    const float* W3   = (const float*)d_in[7];
    const float* b3   = (const float*)d_in[8];

    const int* row = eidx;
    const int* col = eidx + N_EDGES;

    // ws layout (all 64B aligned): P 6.40 MB | buf 5.62 MB | cursor 784 B
    unsigned short* P   = (unsigned short*)d_ws;
    unsigned int*   buf = (unsigned int*)((char*)d_ws + (size_t)N_NODES * 128);
    int* cursor = (int*)((char*)d_ws + (size_t)N_NODES * 128
                         + (size_t)N_BUCKETS * BUCKET_CAP * 4);
    float* out = (float*)d_out;

    // Dispatch 1: zero cursors + precompute P (one tile per wave)
    precompute_P_mfma<<<K1_BLOCKS, 256, 0, stream>>>(x, W1, b1, P, cursor);

    // Dispatch 2: edge MLP + binned scatter (122K cursor atomics total)
    edge_mlp_bin<<<KA_BLOCKS, 256, 0, stream>>>(
        row, col, u, W2, b2, W3, b3, P, buf, cursor);

    // Dispatch 3: per-bucket LDS reduce -> out
    bucket_reduce<<<N_BUCKETS, 256, 0, stream>>>(buf, cursor, out);
}

// Round 9
// 138.456 us; speedup vs baseline: 1.2022x; 1.0846x over previous
//
#include <hip/hip_runtime.h>

#define N_NODES 50000
#define N_EDGES 1200000
#define N_TILES (N_NODES / 16)   // 3125, exact
#define W1T_STRIDE 72            // bf16 elems per j-row in LDS (16B aligned)
#define K1_BLOCKS 782            // 3128 waves >= 3125 tiles, one-shot

#define N_BUCKETS 196            // ceil(50000/256) row buckets of 256 nodes
#define BUCKET_CAP 7168          // mean 6122, sigma ~78 -> 13 sigma headroom
#define EDGES_PER_BLOCK 1920     // KA: binning block size (R8-proven LDS use)
#define KA_BLOCKS 625            // 1.2M / 1920 exact
#define KB_SPLIT 4               // blocks per bucket in the MLP kernel

typedef __attribute__((ext_vector_type(8))) short short8;   // 8 bf16
typedef __attribute__((ext_vector_type(4))) float floatx4;  // MFMA acc

__device__ __forceinline__ unsigned short f32_to_bf16(float f) {
    unsigned int v = __float_as_uint(f);
    unsigned int r = v + 0x7FFFu + ((v >> 16) & 1u);
    return (unsigned short)(r >> 16);
}
__device__ __forceinline__ float bf16_to_f32(unsigned short s) {
    return __uint_as_float(((unsigned int)s) << 16);
}
__device__ __forceinline__ unsigned int pack_bf16x2(float lo, float hi) {
    return (unsigned int)f32_to_bf16(lo) | ((unsigned int)f32_to_bf16(hi) << 16);
}

// ---------------------------------------------------------------------------
// Kernel 1: zero cursors + zero out + layer-1 precompute as MFMA GEMM.
// NEW: P split into P1 (row-halves) and P2 (col-halves), 3.2 MB each, so the
// edge kernel's col working set fits a 4 MiB per-XCD L2.
// P1/P2 row = 32 bf16, position p = 2n+g holds feature (n + 16g); the edge
// kernel loads W2 frags with matching permutation F(q,i)=4q+(i>>1)+16(i&1).
// ---------------------------------------------------------------------------
__global__ __launch_bounds__(256) void precompute_P_mfma(
    const float* __restrict__ x, const float* __restrict__ W1,
    const float* __restrict__ b1,
    unsigned short* __restrict__ P1, unsigned short* __restrict__ P2,
    int* __restrict__ cursor, float* __restrict__ out)
{
    const int tid  = threadIdx.x;
    const int gtid = blockIdx.x * 256 + tid;

    if (gtid < N_BUCKETS) cursor[gtid] = 0;
    for (int i = gtid; i < N_NODES; i += K1_BLOCKS * 256)
        out[i] = 0.0f;   // KB atomically accumulates into out

    __shared__ unsigned short W1t[64 * W1T_STRIDE];   // 9216 B
    for (int e = tid; e < 128 * 32; e += 256) {
        const int kp = e >> 5, jp = e & 31;
        W1t[((kp < 64) ? jp : jp + 32) * W1T_STRIDE + (kp & 63)] =
            f32_to_bf16(W1[e]);
    }
    __syncthreads();

    const int lane = tid & 63;
    const int n = lane & 15;
    const int q = lane >> 4;

    const int tile = blockIdx.x * 4 + (tid >> 6);
    if (tile >= N_TILES) return;

    short8 bw[4][2];
    #pragma unroll
    for (int G = 0; G < 4; ++G)
        #pragma unroll
        for (int h = 0; h < 2; ++h)
            bw[G][h] = *(const short8*)
                &W1t[(n + 16 * G) * W1T_STRIDE + h * 32 + q * 8];
    const float bias0 = b1[n], bias1 = b1[n + 16];

    const int node = tile * 16 + n;
    const float4* xp  = (const float4*)(x + (size_t)node * 64 + q * 8);
    const float4 xa = xp[0], xb = xp[1];
    const float4* xp2 = (const float4*)(x + (size_t)node * 64 + 32 + q * 8);
    const float4 xc = xp2[0], xd = xp2[1];

    short8 a0, a1;
    a0[0] = (short)f32_to_bf16(xa.x); a0[1] = (short)f32_to_bf16(xa.y);
    a0[2] = (short)f32_to_bf16(xa.z); a0[3] = (short)f32_to_bf16(xa.w);
    a0[4] = (short)f32_to_bf16(xb.x); a0[5] = (short)f32_to_bf16(xb.y);
    a0[6] = (short)f32_to_bf16(xb.z); a0[7] = (short)f32_to_bf16(xb.w);
    a1[0] = (short)f32_to_bf16(xc.x); a1[1] = (short)f32_to_bf16(xc.y);
    a1[2] = (short)f32_to_bf16(xc.z); a1[3] = (short)f32_to_bf16(xc.w);
    a1[4] = (short)f32_to_bf16(xd.x); a1[5] = (short)f32_to_bf16(xd.y);
    a1[6] = (short)f32_to_bf16(xd.z); a1[7] = (short)f32_to_bf16(xd.w);

    floatx4 acc[4];
    #pragma unroll
    for (int G = 0; G < 4; ++G) {
        const float bi = (G == 0) ? bias0 : (G == 1) ? bias1 : 0.0f;
        acc[G] = (floatx4){bi, bi, bi, bi};
        acc[G] = __builtin_amdgcn_mfma_f32_16x16x32_bf16(a0, bw[G][0], acc[G], 0, 0, 0);
        acc[G] = __builtin_amdgcn_mfma_f32_16x16x32_bf16(a1, bw[G][1], acc[G], 0, 0, 0);
    }
    unsigned int* P1d = (unsigned int*)P1;
    unsigned int* P2d = (unsigned int*)P2;
    #pragma unroll
    for (int r = 0; r < 4; ++r) {
        const int nr = tile * 16 + q * 4 + r;
        P1d[(size_t)nr * 16 + n] = pack_bf16x2(acc[0][r], acc[1][r]);
        P2d[(size_t)nr * 16 + n] = pack_bf16x2(acc[2][r], acc[3][r]);
    }
}

// ---------------------------------------------------------------------------
// Kernel 2 (KA): bin edge IDs by row bucket. No MLP here. Entry u32 =
// (row & 255) << 24 | col. R8-proven LDS-rank + one global atomic per
// (block, bucket).
// ---------------------------------------------------------------------------
__global__ __launch_bounds__(256) void edge_bin(
    const int* __restrict__ row, const int* __restrict__ col,
    unsigned int* __restrict__ buf, int* __restrict__ cursor)
{
    __shared__ unsigned short rankv[EDGES_PER_BLOCK];  // 3840 B
    __shared__ int hist[N_BUCKETS];
    __shared__ int base[N_BUCKETS];

    const int tid = threadIdx.x;
    for (int b = tid; b < N_BUCKETS; b += 256) hist[b] = 0;
    __syncthreads();

    const int blockStart = blockIdx.x * EDGES_PER_BLOCK;

    for (int i = tid; i < EDGES_PER_BLOCK; i += 256) {
        const int r = row[blockStart + i];
        rankv[i] = (unsigned short)atomicAdd(&hist[r >> 8], 1);
    }
    __syncthreads();

    for (int b = tid; b < N_BUCKETS; b += 256)
        base[b] = atomicAdd(&cursor[b], hist[b]);
    __syncthreads();

    for (int i = tid; i < EDGES_PER_BLOCK; i += 256) {
        const int r = row[blockStart + i];
        const int c = col[blockStart + i];
        const int bin = r >> 8;
        buf[(size_t)bin * BUCKET_CAP + base[bin] + (int)rankv[i]] =
            ((unsigned int)(r & 255) << 24) | (unsigned int)c;
    }
}

// ---------------------------------------------------------------------------
// Kernel 3 (KB): per-bucket MLP (layers 2+3, MFMA) + LDS fp32 row reduce.
// Block = (bucket b, segment s). Row gathers hit P1[256b..256b+255] (16 KB
// hot window); col gathers hit L2-resident P2 (3.2 MB). Row accumulation in
// LDS accs[256]; one global atomicAdd per node per block at the end
// (196*4*256 ~= 200K atomics total).
// ---------------------------------------------------------------------------
__global__ __launch_bounds__(256) void bucket_mlp(
    const float* __restrict__ u,
    const float* __restrict__ W2, const float* __restrict__ b2,
    const float* __restrict__ W3, const float* __restrict__ b3,
    const unsigned short* __restrict__ P1, const unsigned short* __restrict__ P2,
    const unsigned int* __restrict__ buf, const int* __restrict__ cursor,
    float* __restrict__ out)
{
    __shared__ float accs[256];
    const int tid = threadIdx.x;
    accs[tid] = 0.0f;

    const int b = blockIdx.x >> 2;          // bucket
    const int s = blockIdx.x & (KB_SPLIT - 1);

    const int lane = tid & 63;
    const int n = lane & 15;
    const int q = lane >> 4;
    const int wave = tid >> 6;

    // W2/W3 fragments with the P permutation F(q,i)
    short8 bf0, bf1;
    #pragma unroll
    for (int i = 0; i < 8; ++i) {
        const int F = q * 4 + (i >> 1) + 16 * (i & 1);
        bf0[i] = (short)f32_to_bf16(W2[F * 32 + n]);
        bf1[i] = (short)f32_to_bf16(W2[F * 32 + n + 16]);
    }
    const float w3n0 = W3[n], w3n1 = W3[n + 16];
    const float b2n0 = b2[n], b2n1 = b2[n + 16];
    const float bias3 = b3[0];

    __syncthreads();

    const int cnt = cursor[b];
    const unsigned int* bb = buf + (size_t)b * BUCKET_CAP;
    const unsigned short* P1b = P1 + (size_t)b * 256 * 32;  // bucket row window
    const int nch = (cnt + 31) >> 5;

    // chunk ch handled by (segment, wave): ch = (s*4 + wave) + k*16
    #pragma unroll 1
    for (int ch = s * 4 + wave; ch < nch; ch += KB_SPLIT * 4) {
        const int base0 = ch * 32;

        // ---- gather-lane entries (clamped at tail) ----
        int rl[2], cI[2];
        #pragma unroll
        for (int t = 0; t < 2; ++t) {
            int e = base0 + t * 16 + n;
            if (e >= cnt) e = cnt - 1;
            const unsigned int ent = bb[e];
            rl[t] = (int)(ent >> 24);
            cI[t] = (int)(ent & 0x1FFFFu);
        }
        // ---- owner-lane entry (zeroed at tail) ----
        int r2 = 0; float u2 = 0.0f;
        if (n < 8) {
            const int eloc = base0 + 16 * (n >> 2) + 4 * q + (n & 3);
            const unsigned int ent2 = bb[(eloc < cnt) ? eloc : 0];
            r2 = (int)(ent2 >> 24);
            u2 = (eloc < cnt) ? u[ent2 & 0x1FFFFu] : 0.0f;
        }
        // ---- P gathers: row from 16KB window, col from L2-resident P2 ----
        short8 v1[2], v2[2];
        #pragma unroll
        for (int t = 0; t < 2; ++t) {
            v1[t] = *(const short8*)(P1b + (size_t)rl[t] * 32 + q * 8);
            v2[t] = *(const short8*)(P2 + (size_t)cI[t] * 32 + q * 8);
        }

        // ---- layers 2+3 (R4-proven core) ----
        float tr[2][4];
        #pragma unroll
        for (int t = 0; t < 2; ++t) {
            short8 a;
            #pragma unroll
            for (int i = 0; i < 8; ++i) {
                const float f1 = bf16_to_f32((unsigned short)v1[t][i]);
                const float f2 = bf16_to_f32((unsigned short)v2[t][i]);
                a[i] = (short)f32_to_bf16(fmaxf(f1 + f2, 0.0f));
            }
            floatx4 d0 = {b2n0, b2n0, b2n0, b2n0};
            floatx4 d1 = {b2n1, b2n1, b2n1, b2n1};
            d0 = __builtin_amdgcn_mfma_f32_16x16x32_bf16(a, bf0, d0, 0, 0, 0);
            d1 = __builtin_amdgcn_mfma_f32_16x16x32_bf16(a, bf1, d1, 0, 0, 0);
            #pragma unroll
            for (int r = 0; r < 4; ++r)
                tr[t][r] = fmaxf(d0[r], 0.0f) * w3n0 + fmaxf(d1[r], 0.0f) * w3n1;
        }

        #pragma unroll
        for (int mask = 1; mask < 16; mask <<= 1) {
            #pragma unroll
            for (int t = 0; t < 2; ++t)
                #pragma unroll
                for (int r = 0; r < 4; ++r)
                    tr[t][r] += __shfl_xor(tr[t][r], mask, 64);
        }

        if (n < 8) {
            const float va0 = (n & 4) ? tr[1][0] : tr[0][0];
            const float va1 = (n & 4) ? tr[1][1] : tr[0][1];
            const float va2 = (n & 4) ? tr[1][2] : tr[0][2];
            const float va3 = (n & 4) ? tr[1][3] : tr[0][3];
            const float vb0 = (n & 2) ? va2 : va0;
            const float vb1 = (n & 2) ? va3 : va1;
            const float v   = (n & 1) ? vb1 : vb0;
            atomicAdd(&accs[r2], (v + bias3) * u2);
        }
    }

    __syncthreads();

    const int node = b * 256 + tid;
    if (node < N_NODES) {
        const float val = accs[tid];
        atomicAdd(out + node, val);
    }
}

extern "C" void kernel_launch(void* const* d_in, const int* in_sizes, int n_in,
                              void* d_out, int out_size, void* d_ws, size_t ws_size,
                              hipStream_t stream)
{
    const float* x    = (const float*)d_in[0];
    const int*   eidx = (const int*)  d_in[1];   // [2, E] int32
    const float* u    = (const float*)d_in[2];
    const float* W1   = (const float*)d_in[3];
    const float* b1   = (const float*)d_in[4];
    const float* W2   = (const float*)d_in[5];
    const float* b2   = (const float*)d_in[6];
    const float* W3   = (const float*)d_in[7];
    const float* b3   = (const float*)d_in[8];

    const int* row = eidx;
    const int* col = eidx + N_EDGES;

    // ws layout: P1 3.2MB | P2 3.2MB | buf 5.62MB | cursor 784B
    unsigned short* P1 = (unsigned short*)d_ws;
    unsigned short* P2 = (unsigned short*)((char*)d_ws + (size_t)N_NODES * 64);
    unsigned int*  buf = (unsigned int*)((char*)d_ws + (size_t)N_NODES * 128);
    int* cursor = (int*)((char*)d_ws + (size_t)N_NODES * 128
                         + (size_t)N_BUCKETS * BUCKET_CAP * 4);
    float* out = (float*)d_out;

    // D1: zero cursors + zero out + precompute P1/P2
    precompute_P_mfma<<<K1_BLOCKS, 256, 0, stream>>>(x, W1, b1, P1, P2, cursor, out);

    // D2: bin edge IDs by row bucket
    edge_bin<<<KA_BLOCKS, 256, 0, stream>>>(row, col, buf, cursor);

    // D3: per-bucket MLP + LDS reduce -> out
    bucket_mlp<<<N_BUCKETS * KB_SPLIT, 256, 0, stream>>>(
        u, W2, b2, W3, b3, P1, P2, buf, cursor, out);
}

// Round 10
// 135.576 us; speedup vs baseline: 1.2277x; 1.0212x over previous
//
#include <hip/hip_runtime.h>

#define N_NODES 50000
#define N_EDGES 1200000
#define N_TILES (N_NODES / 16)   // 3125, exact
#define W1T_STRIDE 72            // bf16 elems per j-row in LDS (16B aligned)
#define K1_BLOCKS 782            // 3128 waves >= 3125 tiles, one-shot

#define N_BUCKETS 196            // ceil(50000/256) row buckets of 256 nodes
#define BUCKET_CAP 7168          // mean 6122, sigma ~78 -> 13 sigma headroom
#define EDGES_PER_BLOCK 1920     // binning block size (R8-proven LDS use)
#define KA_BLOCKS 625            // 1.2M / 1920 exact
#define D1_BLOCKS (K1_BLOCKS + KA_BLOCKS)   // 1407: precompute + bin fused
#define KB_SPLIT 4               // segments per bucket in the MLP kernel

typedef __attribute__((ext_vector_type(8))) short short8;   // 8 bf16
typedef __attribute__((ext_vector_type(4))) float floatx4;  // MFMA acc

__device__ __forceinline__ unsigned short f32_to_bf16(float f) {
    unsigned int v = __float_as_uint(f);
    unsigned int r = v + 0x7FFFu + ((v >> 16) & 1u);
    return (unsigned short)(r >> 16);
}
__device__ __forceinline__ float bf16_to_f32(unsigned short s) {
    return __uint_as_float(((unsigned int)s) << 16);
}
__device__ __forceinline__ unsigned int pack_bf16x2(float lo, float hi) {
    return (unsigned int)f32_to_bf16(lo) | ((unsigned int)f32_to_bf16(hi) << 16);
}

// ---------------------------------------------------------------------------
// Dispatch 1 (fused): blocks [0, K1_BLOCKS) do layer-1 precompute (MFMA GEMM,
// R4-proven) + zero `out`; blocks [K1_BLOCKS, D1_BLOCKS) bin edge IDs by row
// bucket (R8-proven rank machinery). The two halves are data-independent and
// run concurrently. `cursor` is pre-zeroed by hipMemsetAsync on the stream.
//
// P1 (row-halves) / P2 (col-halves): 32 bf16 per node, 3.2 MB each (P2 is
// L2-resident in KB). Position p = 2n+g holds feature (n + 16g); KB loads W2
// fragments with the matching permutation F(q,i) = 4q + (i>>1) + 16(i&1).
// Bin entry u32 = (row & 255) << 24 | col.
// ---------------------------------------------------------------------------
__global__ __launch_bounds__(256) void fused_pre_bin(
    const float* __restrict__ x, const float* __restrict__ W1,
    const float* __restrict__ b1,
    const int* __restrict__ row, const int* __restrict__ col,
    unsigned short* __restrict__ P1, unsigned short* __restrict__ P2,
    unsigned int* __restrict__ buf, int* __restrict__ cursor,
    float* __restrict__ out)
{
    __shared__ union {
        unsigned short W1t[64 * W1T_STRIDE];                // 9216 B
        struct {
            unsigned short rankv[EDGES_PER_BLOCK];          // 3840 B
            int hist[N_BUCKETS];                            //  784 B
            int base[N_BUCKETS];                            //  784 B
        } bin;
    } sh;

    const int tid = threadIdx.x;
    const int bid = blockIdx.x;

    if (bid < K1_BLOCKS) {
        // ================= precompute path =================
        const int gtid = bid * 256 + tid;
        for (int i = gtid; i < N_NODES; i += K1_BLOCKS * 256)
            out[i] = 0.0f;   // KB atomically accumulates into out

        for (int e = tid; e < 128 * 32; e += 256) {
            const int kp = e >> 5, jp = e & 31;
            sh.W1t[((kp < 64) ? jp : jp + 32) * W1T_STRIDE + (kp & 63)] =
                f32_to_bf16(W1[e]);
        }
        __syncthreads();

        const int lane = tid & 63;
        const int n = lane & 15;
        const int q = lane >> 4;

        const int tile = bid * 4 + (tid >> 6);
        if (tile >= N_TILES) return;

        short8 bw[4][2];
        #pragma unroll
        for (int G = 0; G < 4; ++G)
            #pragma unroll
            for (int h = 0; h < 2; ++h)
                bw[G][h] = *(const short8*)
                    &sh.W1t[(n + 16 * G) * W1T_STRIDE + h * 32 + q * 8];
        const float bias0 = b1[n], bias1 = b1[n + 16];

        const int node = tile * 16 + n;
        const float4* xp  = (const float4*)(x + (size_t)node * 64 + q * 8);
        const float4 xa = xp[0], xb = xp[1];
        const float4* xp2 = (const float4*)(x + (size_t)node * 64 + 32 + q * 8);
        const float4 xc = xp2[0], xd = xp2[1];

        short8 a0, a1;
        a0[0] = (short)f32_to_bf16(xa.x); a0[1] = (short)f32_to_bf16(xa.y);
        a0[2] = (short)f32_to_bf16(xa.z); a0[3] = (short)f32_to_bf16(xa.w);
        a0[4] = (short)f32_to_bf16(xb.x); a0[5] = (short)f32_to_bf16(xb.y);
        a0[6] = (short)f32_to_bf16(xb.z); a0[7] = (short)f32_to_bf16(xb.w);
        a1[0] = (short)f32_to_bf16(xc.x); a1[1] = (short)f32_to_bf16(xc.y);
        a1[2] = (short)f32_to_bf16(xc.z); a1[3] = (short)f32_to_bf16(xc.w);
        a1[4] = (short)f32_to_bf16(xd.x); a1[5] = (short)f32_to_bf16(xd.y);
        a1[6] = (short)f32_to_bf16(xd.z); a1[7] = (short)f32_to_bf16(xd.w);

        floatx4 acc[4];
        #pragma unroll
        for (int G = 0; G < 4; ++G) {
            const float bi = (G == 0) ? bias0 : (G == 1) ? bias1 : 0.0f;
            acc[G] = (floatx4){bi, bi, bi, bi};
            acc[G] = __builtin_amdgcn_mfma_f32_16x16x32_bf16(a0, bw[G][0], acc[G], 0, 0, 0);
            acc[G] = __builtin_amdgcn_mfma_f32_16x16x32_bf16(a1, bw[G][1], acc[G], 0, 0, 0);
        }
        unsigned int* P1d = (unsigned int*)P1;
        unsigned int* P2d = (unsigned int*)P2;
        #pragma unroll
        for (int r = 0; r < 4; ++r) {
            const int nr = tile * 16 + q * 4 + r;
            P1d[(size_t)nr * 16 + n] = pack_bf16x2(acc[0][r], acc[1][r]);
            P2d[(size_t)nr * 16 + n] = pack_bf16x2(acc[2][r], acc[3][r]);
        }
    } else {
        // ================= binning path =================
        for (int b = tid; b < N_BUCKETS; b += 256) sh.bin.hist[b] = 0;
        __syncthreads();

        const int blockStart = (bid - K1_BLOCKS) * EDGES_PER_BLOCK;

        for (int i = tid; i < EDGES_PER_BLOCK; i += 256) {
            const int r = row[blockStart + i];
            sh.bin.rankv[i] = (unsigned short)atomicAdd(&sh.bin.hist[r >> 8], 1);
        }
        __syncthreads();

        for (int b = tid; b < N_BUCKETS; b += 256)
            sh.bin.base[b] = atomicAdd(&cursor[b], sh.bin.hist[b]);
        __syncthreads();

        for (int i = tid; i < EDGES_PER_BLOCK; i += 256) {
            const int r = row[blockStart + i];
            const int c = col[blockStart + i];
            const int bin = r >> 8;
            buf[(size_t)bin * BUCKET_CAP + sh.bin.base[bin] + (int)sh.bin.rankv[i]] =
                ((unsigned int)(r & 255) << 24) | (unsigned int)c;
        }
    }
}

// ---------------------------------------------------------------------------
// Dispatch 2 (KB): per-bucket MLP (layers 2+3, MFMA) + LDS fp32 row reduce.
// 512-thread blocks: 8 waves share one accs[256] -> 2x TLP vs R9 at the same
// 200K final out-atomics. Block = (bucket b, segment s); wave-slot = s*8+wave,
// chunk stride = 32. Row gathers hit the 16 KB P1 bucket window (L1); col
// gathers hit L2-resident P2 (3.2 MB).
// ---------------------------------------------------------------------------
__global__ __launch_bounds__(512) void bucket_mlp(
    const float* __restrict__ u,
    const float* __restrict__ W2, const float* __restrict__ b2,
    const float* __restrict__ W3, const float* __restrict__ b3,
    const unsigned short* __restrict__ P1, const unsigned short* __restrict__ P2,
    const unsigned int* __restrict__ buf, const int* __restrict__ cursor,
    float* __restrict__ out)
{
    __shared__ float accs[256];
    const int tid = threadIdx.x;
    if (tid < 256) accs[tid] = 0.0f;

    const int b = blockIdx.x >> 2;              // bucket
    const int s = blockIdx.x & (KB_SPLIT - 1);  // segment

    const int lane = tid & 63;
    const int n = lane & 15;
    const int q = lane >> 4;
    const int wave = tid >> 6;                  // 0..7

    // W2/W3 fragments with the P permutation F(q,i)
    short8 bf0, bf1;
    #pragma unroll
    for (int i = 0; i < 8; ++i) {
        const int F = q * 4 + (i >> 1) + 16 * (i & 1);
        bf0[i] = (short)f32_to_bf16(W2[F * 32 + n]);
        bf1[i] = (short)f32_to_bf16(W2[F * 32 + n + 16]);
    }
    const float w3n0 = W3[n], w3n1 = W3[n + 16];
    const float b2n0 = b2[n], b2n1 = b2[n + 16];
    const float bias3 = b3[0];

    __syncthreads();

    const int cnt = cursor[b];
    const unsigned int* bb = buf + (size_t)b * BUCKET_CAP;
    const unsigned short* P1b = P1 + (size_t)b * 256 * 32;  // bucket row window
    const int nch = (cnt + 31) >> 5;

    #pragma unroll 1
    for (int ch = s * 8 + wave; ch < nch; ch += KB_SPLIT * 8) {
        const int base0 = ch * 32;

        // ---- gather-lane entries (clamped at tail) ----
        int rl[2], cI[2];
        #pragma unroll
        for (int t = 0; t < 2; ++t) {
            int e = base0 + t * 16 + n;
            if (e >= cnt) e = cnt - 1;
            const unsigned int ent = bb[e];
            rl[t] = (int)(ent >> 24);
            cI[t] = (int)(ent & 0x1FFFFu);
        }
        // ---- owner-lane entry (zeroed at tail) ----
        int r2 = 0; float u2 = 0.0f;
        if (n < 8) {
            const int eloc = base0 + 16 * (n >> 2) + 4 * q + (n & 3);
            const unsigned int ent2 = bb[(eloc < cnt) ? eloc : 0];
            r2 = (int)(ent2 >> 24);
            u2 = (eloc < cnt) ? u[ent2 & 0x1FFFFu] : 0.0f;
        }
        // ---- P gathers: row from 16KB window, col from L2-resident P2 ----
        short8 v1[2], v2[2];
        #pragma unroll
        for (int t = 0; t < 2; ++t) {
            v1[t] = *(const short8*)(P1b + (size_t)rl[t] * 32 + q * 8);
            v2[t] = *(const short8*)(P2 + (size_t)cI[t] * 32 + q * 8);
        }

        // ---- layers 2+3 (R4-proven core) ----
        float tr[2][4];
        #pragma unroll
        for (int t = 0; t < 2; ++t) {
            short8 a;
            #pragma unroll
            for (int i = 0; i < 8; ++i) {
                const float f1 = bf16_to_f32((unsigned short)v1[t][i]);
                const float f2 = bf16_to_f32((unsigned short)v2[t][i]);
                a[i] = (short)f32_to_bf16(fmaxf(f1 + f2, 0.0f));
            }
            floatx4 d0 = {b2n0, b2n0, b2n0, b2n0};
            floatx4 d1 = {b2n1, b2n1, b2n1, b2n1};
            d0 = __builtin_amdgcn_mfma_f32_16x16x32_bf16(a, bf0, d0, 0, 0, 0);
            d1 = __builtin_amdgcn_mfma_f32_16x16x32_bf16(a, bf1, d1, 0, 0, 0);
            #pragma unroll
            for (int r = 0; r < 4; ++r)
                tr[t][r] = fmaxf(d0[r], 0.0f) * w3n0 + fmaxf(d1[r], 0.0f) * w3n1;
        }

        #pragma unroll
        for (int mask = 1; mask < 16; mask <<= 1) {
            #pragma unroll
            for (int t = 0; t < 2; ++t)
                #pragma unroll
                for (int r = 0; r < 4; ++r)
                    tr[t][r] += __shfl_xor(tr[t][r], mask, 64);
        }

        if (n < 8) {
            const float va0 = (n & 4) ? tr[1][0] : tr[0][0];
            const float va1 = (n & 4) ? tr[1][1] : tr[0][1];
            const float va2 = (n & 4) ? tr[1][2] : tr[0][2];
            const float va3 = (n & 4) ? tr[1][3] : tr[0][3];
            const float vb0 = (n & 2) ? va2 : va0;
            const float vb1 = (n & 2) ? va3 : va1;
            const float v   = (n & 1) ? vb1 : vb0;
            atomicAdd(&accs[r2], (v + bias3) * u2);
        }
    }

    __syncthreads();

    if (tid < 256) {
        const int node = b * 256 + tid;
        if (node < N_NODES) atomicAdd(out + node, accs[tid]);
    }
}

extern "C" void kernel_launch(void* const* d_in, const int* in_sizes, int n_in,
                              void* d_out, int out_size, void* d_ws, size_t ws_size,
                              hipStream_t stream)
{
    const float* x    = (const float*)d_in[0];
    const int*   eidx = (const int*)  d_in[1];   // [2, E] int32
    const float* u    = (const float*)d_in[2];
    const float* W1   = (const float*)d_in[3];
    const float* b1   = (const float*)d_in[4];
    const float* W2   = (const float*)d_in[5];
    const float* b2   = (const float*)d_in[6];
    const float* W3   = (const float*)d_in[7];
    const float* b3   = (const float*)d_in[8];

    const int* row = eidx;
    const int* col = eidx + N_EDGES;

    // ws layout: P1 3.2MB | P2 3.2MB | buf 5.62MB | cursor 784B
    unsigned short* P1 = (unsigned short*)d_ws;
    unsigned short* P2 = (unsigned short*)((char*)d_ws + (size_t)N_NODES * 64);
    unsigned int*  buf = (unsigned int*)((char*)d_ws + (size_t)N_NODES * 128);
    int* cursor = (int*)((char*)d_ws + (size_t)N_NODES * 128
                         + (size_t)N_BUCKETS * BUCKET_CAP * 4);
    float* out = (float*)d_out;

    // zero bucket cursors (784 B, must precede the binning blocks of D1)
    hipMemsetAsync(cursor, 0, N_BUCKETS * sizeof(int), stream);

    // D1: precompute P1/P2 + zero out  ||  bin edge IDs (concurrent halves)
    fused_pre_bin<<<D1_BLOCKS, 256, 0, stream>>>(
        x, W1, b1, row, col, P1, P2, buf, cursor, out);

    // D2: per-bucket MLP + LDS reduce -> out (512-thread blocks)
    bucket_mlp<<<N_BUCKETS * KB_SPLIT, 512, 0, stream>>>(
        u, W2, b2, W3, b3, P1, P2, buf, cursor, out);
}